// Round 2
// 312.570 us; speedup vs baseline: 1.0166x; 1.0166x over previous
//
#include <hip/hip_runtime.h>
#include <hip/hip_fp16.h>
#include <math.h>

namespace {

constexpr int NN = 100000;   // nodes
constexpr int NE = 1000000;  // edges
constexpr int D  = 64;       // feature dim

constexpr int RPB_LOG = 10;                       // rows per bucket = 1024
constexpr int RPB = 1 << RPB_LOG;
constexpr int NBUK = (NN + RPB - 1) >> RPB_LOG;   // 98 buckets
constexpr int CAP = 16384;                        // bucket capacity (mean 10.2K)
constexpr int TILE = 2048;                        // edges per bin tile
constexpr int NTILES = (NE + TILE - 1) / TILE;    // 489

using ushort_t = unsigned short;
typedef __attribute__((ext_vector_type(8))) short short8;  // 8 bf16 (4 VGPRs)
typedef __attribute__((ext_vector_type(4))) float f32x4;   // MFMA 16x16 accumulator

union FragU { uint4 v; short8 s; };

// split two fp32 into packed bf16 hi parts and packed bf16 lo (residual) parts.
__device__ inline void split2(float f0, float f1, unsigned int& hi, unsigned int& lo) {
    unsigned int u0 = __float_as_uint(f0);
    unsigned int u1 = __float_as_uint(f1);
    hi = (u0 >> 16) | (u1 & 0xffff0000u);
    float l0 = f0 - __uint_as_float(u0 & 0xffff0000u);
    float l1 = f1 - __uint_as_float(u1 & 0xffff0000u);
    lo = (__float_as_uint(l0) >> 16) | (__float_as_uint(l1) & 0xffff0000u);
}

__device__ inline unsigned int packh(float a, float b) {   // 2x fp16 (RNE) packed
    union { __half2 h; unsigned int u; } cv;
    cv.h = __float22half2_rn(make_float2(a, b));
    return cv.u;
}

__device__ inline float2 h2f(unsigned int v) {
    union { unsigned int u; __half2 h; } cv;
    cv.u = v;
    return __half22float2(cv.h);
}

__global__ void iperm_k(const int* __restrict__ perm, int* __restrict__ iperm, int n) {
    int i = blockIdx.x * blockDim.x + threadIdx.x;
    if (i < n) {
        iperm[perm[i]] = i;
    }
}

// Precompute A-operand fragments (A = W^T, M = out-feature) for the MFMA GEMM.
// Layout per weight matrix: [ftile(4)][ktile(2)][hi/lo(2)][lane(64)] x 16B.
// Lane l holds A[m][k] with m = ft*16 + (l&15), k = kt*32 + (l>>4)*8 + j.
__global__ void wfrag_k(const float* __restrict__ W1, const float* __restrict__ W2,
                        uint4* __restrict__ fb) {
    int lane = threadIdx.x;
    for (int w = 0; w < 2; ++w) {
        const float* W = (w != 0) ? W2 : W1;
        uint4* out = fb + w * 1024;
        for (int ft = 0; ft < 4; ++ft) {
            for (int kt = 0; kt < 2; ++kt) {
                int m  = ft * 16 + (lane & 15);
                int k0 = kt * 32 + (lane >> 4) * 8;
                unsigned int hi0, lo0, hi1, lo1, hi2, lo2, hi3, lo3;
                split2(W[(k0 + 0) * 64 + m], W[(k0 + 1) * 64 + m], hi0, lo0);
                split2(W[(k0 + 2) * 64 + m], W[(k0 + 3) * 64 + m], hi1, lo1);
                split2(W[(k0 + 4) * 64 + m], W[(k0 + 5) * 64 + m], hi2, lo2);
                split2(W[(k0 + 6) * 64 + m], W[(k0 + 7) * 64 + m], hi3, lo3);
                out[((ft * 2 + kt) * 2 + 0) * 64 + lane] = make_uint4(hi0, hi1, hi2, hi3);
                out[((ft * 2 + kt) * 2 + 1) * 64 + lane] = make_uint4(lo0, lo1, lo2, lo3);
            }
        }
    }
}

// Phase A: bin edges into 98 fixed-capacity row-range buckets.
// Payload packed: (r & 1023) << 17 | c   (c < 2^17)
__global__ void bin_k(const int* __restrict__ rows, const int* __restrict__ cols,
                      int* __restrict__ bcount, unsigned int* __restrict__ binned, int e) {
    __shared__ int hist[NBUK];
    __shared__ int gbase[NBUK];
    __shared__ int lofs[NBUK];
    int base = blockIdx.x * TILE;
    for (int i = threadIdx.x; i < NBUK; i += blockDim.x) {
        hist[i] = 0;
        lofs[i] = 0;
    }
    __syncthreads();
    int r[8];
    int c[8];
    int bk[8];
#pragma unroll
    for (int j = 0; j < 8; ++j) {
        int i = base + j * 256 + threadIdx.x;
        if (i < e) {
            r[j] = rows[i];
            c[j] = cols[i];
            bk[j] = r[j] >> RPB_LOG;
            atomicAdd(&hist[bk[j]], 1);
        } else {
            bk[j] = -1;
        }
    }
    __syncthreads();
    if (threadIdx.x < NBUK) {
        int h = hist[threadIdx.x];
        gbase[threadIdx.x] = h ? atomicAdd(&bcount[threadIdx.x], h) : 0;
    }
    __syncthreads();
#pragma unroll
    for (int j = 0; j < 8; ++j) {
        if (bk[j] >= 0) {
            int l = gbase[bk[j]] + atomicAdd(&lofs[bk[j]], 1);
            if (l < CAP) {
                unsigned int v = ((unsigned int)(r[j] & (RPB - 1)) << 17) | (unsigned int)c[j];
                binned[(size_t)bk[j] * CAP + l] = v;
            }
        }
    }
}

// exclusive scan of the 98 bucket counts -> bucket bases in scols
__global__ void bucket_base_k(const int* __restrict__ bcount, int* __restrict__ bbase) {
    __shared__ int sm[128];
    int t = threadIdx.x;
    int v = (t < NBUK) ? bcount[t] : 0;
    sm[t] = v;
    __syncthreads();
    for (int off = 1; off < 128; off <<= 1) {
        int u = (t >= off) ? sm[t - off] : 0;
        __syncthreads();
        sm[t] += u;
        __syncthreads();
    }
    if (t < NBUK) {
        bbase[t] = sm[t] - v;  // exclusive
    }
}

// Phase B: per-bucket counting sort + per-row deg/rowstart/dis production.
__global__ void bucket_sort_k(const unsigned int* __restrict__ binned,
                              const int* __restrict__ bcount, const int* __restrict__ bbase,
                              int* __restrict__ scols, int* __restrict__ rowstart,
                              int* __restrict__ deg, float* __restrict__ dis) {
    __shared__ int lcur[RPB];
    __shared__ int srs[RPB];
    __shared__ int wsum[16];
    int b = blockIdx.x;
    int row0 = b << RPB_LOG;
    int nrows = min(RPB, NN - row0);
    int cnt = bcount[b];
    const unsigned int* src = binned + (size_t)b * CAP;
    int tid = threadIdx.x;
    lcur[tid] = 0;
    __syncthreads();
    for (int i = tid; i < cnt; i += RPB) {
        atomicAdd(&lcur[src[i] >> 17], 1);
    }
    __syncthreads();
    int d = (tid < nrows) ? lcur[tid] : 0;
    int lane = tid & 63;
    int wid = tid >> 6;
    int inc = d;
#pragma unroll
    for (int off = 1; off < 64; off <<= 1) {
        int t = __shfl_up(inc, off);
        if (lane >= off) inc += t;
    }
    if (lane == 63) wsum[wid] = inc;
    __syncthreads();
    int wpre = 0;
    for (int w = 0; w < wid; ++w) wpre += wsum[w];
    int gstart = bbase[b] + wpre + inc - d;   // global exclusive prefix
    if (tid < nrows) {
        rowstart[row0 + tid] = gstart;
        deg[row0 + tid] = d;
        dis[row0 + tid] = rsqrtf((float)(d + 1));  // +1 self-loop
    }
    __syncthreads();
    srs[tid] = gstart;
    lcur[tid] = 0;
    __syncthreads();
    for (int i = tid; i < cnt; i += RPB) {
        unsigned int v = src[i];
        int rl = (int)(v >> 17);
        int pos = srs[rl] + atomicAdd(&lcur[rl], 1);
        scols[pos] = (int)(v & 0x1FFFFu);
    }
}

// MFMA GEMM: D = W^T · X^T via mfma_f32_16x16x32_bf16 with bf16 hi/lo split
// (hi*hi + hi*lo + lo*hi => ~fp32 accuracy). One wave per 16-node tile; the
// wave's 4 accumulators cover the 4 out-feature tiles. C/D layout:
// col=lane&15 -> node, row=(lane>>4)*4+reg -> feature, so each lane holds 4
// consecutive features of one node -> one 8B packed-fp16 store per ftile/half.
// Epilogue writes the interleaved dual-table tPN (row = 256B: [P 64 f16 | N 64 f16]):
//   mode 1 (layer 1): P-half dense at node (scale dis[node]); N-half scattered
//                     to q=iperm[node] (scale dis[q]).
//   mode 2 (layer 2): rows < nmod are P (off 0), rows >= nmod are N (off 64),
//                     both scaled by dis[rm].
__global__ void gemm64_mfma_k(const float* __restrict__ in, const uint4* __restrict__ wf,
                              ushort_t* __restrict__ tPN, const int* __restrict__ iperm,
                              const float* __restrict__ dis, int n, int nmod, int mode) {
    int lane  = threadIdx.x & 63;
    int wtile = (int)((blockIdx.x * blockDim.x + threadIdx.x) >> 6);
    if (wtile * 16 >= n) return;
    int node = wtile * 16 + (lane & 15);
    int kg   = lane >> 4;  // 0..3

    FragU whi[4][2];
    FragU wlo[4][2];
#pragma unroll
    for (int ft = 0; ft < 4; ++ft) {
#pragma unroll
        for (int kt = 0; kt < 2; ++kt) {
            whi[ft][kt].v = wf[((ft * 2 + kt) * 2 + 0) * 64 + lane];
            wlo[ft][kt].v = wf[((ft * 2 + kt) * 2 + 1) * 64 + lane];
        }
    }

    const float4* xr = (const float4*)in;
    size_t rbase = (size_t)node * 16 + (size_t)(kg * 2);
    f32x4 acc[4];
#pragma unroll
    for (int ft = 0; ft < 4; ++ft) {
        acc[ft] = f32x4{0.f, 0.f, 0.f, 0.f};
    }

#pragma unroll
    for (int kt = 0; kt < 2; ++kt) {
        // B-frag: X^T, lane holds x[node][kt*32 + kg*8 + j], j=0..7
        float4 a0 = xr[rbase + kt * 8];
        float4 a1 = xr[rbase + kt * 8 + 1];
        unsigned int h0, l0, h1, l1, h2, l2, h3, l3;
        split2(a0.x, a0.y, h0, l0);
        split2(a0.z, a0.w, h1, l1);
        split2(a1.x, a1.y, h2, l2);
        split2(a1.z, a1.w, h3, l3);
        FragU xhi;
        FragU xlo;
        xhi.v = make_uint4(h0, h1, h2, h3);
        xlo.v = make_uint4(l0, l1, l2, l3);
#pragma unroll
        for (int ft = 0; ft < 4; ++ft) {
            acc[ft] = __builtin_amdgcn_mfma_f32_16x16x32_bf16(whi[ft][kt].s, xhi.s, acc[ft], 0, 0, 0);
            acc[ft] = __builtin_amdgcn_mfma_f32_16x16x32_bf16(whi[ft][kt].s, xlo.s, acc[ft], 0, 0, 0);
            acc[ft] = __builtin_amdgcn_mfma_f32_16x16x32_bf16(wlo[ft][kt].s, xhi.s, acc[ft], 0, 0, 0);
        }
    }

    int fo = kg * 4;  // feature offset inside ftile (4 consecutive feats per lane)
    if (mode == 1) {
        float sP = dis[node];
        int q = iperm[node];
        float sN = dis[q];
        ushort_t* pP = tPN + (size_t)node * 128;
        ushort_t* pN = tPN + (size_t)q * 128 + 64;
#pragma unroll
        for (int ft = 0; ft < 4; ++ft) {
            uint2 up = make_uint2(packh(sP * acc[ft][0], sP * acc[ft][1]),
                                  packh(sP * acc[ft][2], sP * acc[ft][3]));
            *(uint2*)(pP + ft * 16 + fo) = up;
            uint2 un = make_uint2(packh(sN * acc[ft][0], sN * acc[ft][1]),
                                  packh(sN * acc[ft][2], sN * acc[ft][3]));
            *(uint2*)(pN + ft * 16 + fo) = un;
        }
    } else {
        int rm  = (node >= nmod) ? node - nmod : node;
        int off = (node >= nmod) ? 64 : 0;
        float s = dis[rm];
        ushort_t* p = tPN + (size_t)rm * 128 + off;
#pragma unroll
        for (int ft = 0; ft < 4; ++ft) {
            uint2 u = make_uint2(packh(s * acc[ft][0], s * acc[ft][1]),
                                 packh(s * acc[ft][2], s * acc[ft][3]));
            *(uint2*)(p + ft * 16 + fo) = u;
        }
    }
}

// Dual gather-aggregate over the interleaved fp16 table. One wave per row;
// lanes 0-31 = P half, 32-63 = N half; each lane covers 2 features via one 4B load.
// outX[r] = dis[r]*(sum_j tX[c_j] + tX[r]) + b  (+ optional PReLU)
__global__ void agg_dual_k(const ushort_t* __restrict__ tPN,
                           float* __restrict__ dstP, float* __restrict__ dstN,
                           const float* __restrict__ dis,
                           const int* __restrict__ rowstart, const int* __restrict__ deg,
                           const int* __restrict__ scols,
                           const float* __restrict__ bias, const float* __restrict__ prelu_a,
                           int n) {
    int lane = threadIdx.x & 63;
    int hl = lane & 31;
    int half = lane >> 5;
    int r = blockIdx.x * (blockDim.x >> 6) + (threadIdx.x >> 6);
    if (r >= n) return;
    int rs   = __builtin_amdgcn_readfirstlane(r);
    int base = __builtin_amdgcn_readfirstlane(rowstart[rs]);
    int dg   = __builtin_amdgcn_readfirstlane(deg[rs]);
    float dr = dis[rs];
    size_t lofs = (size_t)(half * 64 + hl * 2);
    unsigned int sv = *(const unsigned int*)(tPN + (size_t)rs * 128 + lofs);
    float2 fs = h2f(sv);
    float a0 = fs.x;
    float a1 = fs.y;     // self-loop term
    int j = 0;
    for (; j + 4 <= dg; j += 4) {
        int c0 = scols[base + j];
        int c1 = scols[base + j + 1];
        int c2 = scols[base + j + 2];
        int c3 = scols[base + j + 3];
        unsigned int v0 = *(const unsigned int*)(tPN + (size_t)c0 * 128 + lofs);
        unsigned int v1 = *(const unsigned int*)(tPN + (size_t)c1 * 128 + lofs);
        unsigned int v2 = *(const unsigned int*)(tPN + (size_t)c2 * 128 + lofs);
        unsigned int v3 = *(const unsigned int*)(tPN + (size_t)c3 * 128 + lofs);
        float2 f0 = h2f(v0);
        float2 f1 = h2f(v1);
        float2 f2 = h2f(v2);
        float2 f3 = h2f(v3);
        a0 += f0.x + f1.x + f2.x + f3.x;
        a1 += f0.y + f1.y + f2.y + f3.y;
    }
    for (; j < dg; ++j) {
        int c = scols[base + j];
        unsigned int v = *(const unsigned int*)(tPN + (size_t)c * 128 + lofs);
        float2 f = h2f(v);
        a0 += f.x;
        a1 += f.y;
    }
    float2 bv = *(const float2*)(bias + 2 * hl);
    float v0 = fmaf(dr, a0, bv.x);
    float v1 = fmaf(dr, a1, bv.y);
    if (prelu_a) {
        float a = *prelu_a;
        v0 = v0 >= 0.f ? v0 : a * v0;
        v1 = v1 >= 0.f ? v1 : a * v1;
    }
    float* dst = half ? dstN : dstP;
    *(float2*)(dst + (size_t)rs * D + 2 * hl) = float2{v0, v1};
}

__global__ void summary_partial_k(const float* __restrict__ pos, float* __restrict__ acc, int n) {
    int lane = threadIdx.x & 63;
    int wave = (blockIdx.x * blockDim.x + threadIdx.x) >> 6;
    int nw = (gridDim.x * blockDim.x) >> 6;
    float s = 0.f;
    for (int r = wave; r < n; r += nw) {
        s += pos[(size_t)r * D + lane];
    }
    atomicAdd(&acc[lane], s);
}

__global__ void summary_final_k(const float* __restrict__ acc, float* __restrict__ out, int n) {
    int f = threadIdx.x;
    if (f < D) {
        float m = acc[f] / (float)n;
        out[f] = 1.f / (1.f + expf(-m));
    }
}

} // namespace

extern "C" void kernel_launch(void* const* d_in, const int* in_sizes, int n_in,
                              void* d_out, int out_size, void* d_ws, size_t ws_size,
                              hipStream_t stream) {
    (void)in_sizes; (void)n_in; (void)out_size; (void)ws_size;
    const float* x       = (const float*)d_in[0];
    const int*   ei      = (const int*)  d_in[1];
    const int*   perm    = (const int*)  d_in[2];
    const float* W1      = (const float*)d_in[3];
    const float* b1      = (const float*)d_in[4];
    const float* prelu_a = (const float*)d_in[5];
    const float* W2      = (const float*)d_in[6];
    const float* b2      = (const float*)d_in[7];

    float* outP = (float*)d_out;
    float* outN = outP + (size_t)NN * D;
    float* outS = outN + (size_t)NN * D;

    const int* erows = ei;
    const int* ecols = ei + NE;

    char* ws = (char*)d_ws;
    size_t off = 0;
    auto alloc = [&](size_t bytes) {
        void* p = ws + off;
        off = (off + bytes + 255) & ~(size_t)255;
        return p;
    };
    int*      deg      = (int*)     alloc((size_t)NN * 4);
    float*    dis      = (float*)   alloc((size_t)NN * 4);
    int*      rowstart = (int*)     alloc((size_t)NN * 4);
    int*      iperm    = (int*)     alloc((size_t)NN * 4);
    int*      bcount   = (int*)     alloc((size_t)NBUK * 4);
    int*      bbase    = (int*)     alloc((size_t)NBUK * 4);
    unsigned int* binned = (unsigned int*)alloc((size_t)NBUK * CAP * 4);  // 6.4 MB
    int*      scols    = (int*)     alloc((size_t)NE * 4);
    ushort_t* tPN      = (ushort_t*)alloc((size_t)NN * 128 * 2);   // interleaved dual table (fp16), 25.6 MB
    float*    aggPN    = (float*)   alloc((size_t)2 * NN * D * 4); // [aggP | aggN], 51.2 MB
    float*    aggP     = aggPN;
    float*    aggN     = aggPN + (size_t)NN * D;
    float*    acc      = (float*)   alloc((size_t)D * 4);
    uint4*    wfrag    = (uint4*)   alloc((size_t)2 * 1024 * 16);  // W1|W2 bf16 hi/lo frags, 32 KB
    // ~90 MB total

    hipMemsetAsync(bcount, 0, (size_t)NBUK * 4, stream);
    hipMemsetAsync(acc, 0, (size_t)D * 4, stream);

    // graph preprocessing: bin -> base scan -> per-bucket sort (+deg/rowstart/dis)
    iperm_k<<<(NN + 255) / 256, 256, 0, stream>>>(perm, iperm, NN);
    wfrag_k<<<1, 64, 0, stream>>>(W1, W2, wfrag);
    bin_k<<<NTILES, 256, 0, stream>>>(erows, ecols, bcount, binned, NE);
    bucket_base_k<<<1, 128, 0, stream>>>(bcount, bbase);
    bucket_sort_k<<<NBUK, RPB, 0, stream>>>(binned, bcount, bbase, scols, rowstart, deg, dis);

    const int aggBlocks = (NN + 3) / 4;

    // layer 1: tPN[c] = [dis[c]*xw[c] | dis[c]*xw[perm[c]]]  (one MFMA gemm, fused scatter)
    gemm64_mfma_k<<<(NN / 16 + 3) / 4, 256, 0, stream>>>(x, wfrag, tPN, iperm, dis, NN, NN, 1);
    agg_dual_k<<<aggBlocks, 256, 0, stream>>>(tPN, aggP, aggN, dis, rowstart, deg,
                                              scols, b1, prelu_a, NN);

    // layer 2: one MFMA gemm over [aggP|aggN] (200k rows) -> interleaved scaled table
    gemm64_mfma_k<<<(2 * NN / 16 + 3) / 4, 256, 0, stream>>>(aggPN, wfrag + 1024, tPN, nullptr,
                                                             dis, 2 * NN, NN, 2);
    agg_dual_k<<<aggBlocks, 256, 0, stream>>>(tPN, outP, outN, dis, rowstart, deg,
                                              scols, b2, nullptr, NN);

    // summary = sigmoid(mean(positive, axis=0))
    summary_partial_k<<<256, 256, 0, stream>>>(outP, acc, NN);
    summary_final_k<<<1, 64, 0, stream>>>(acc, outS, NN);
}